// Round 14
// baseline (653.649 us; speedup 1.0000x reference)
//
#include <hip/hip_runtime.h>
#include <stdint.h>

typedef _Float16 f16;
typedef _Float16 f16x2 __attribute__((ext_vector_type(2)));
typedef _Float16 f16x4 __attribute__((ext_vector_type(4)));
typedef _Float16 f16x8 __attribute__((ext_vector_type(8)));
typedef float f32x4 __attribute__((ext_vector_type(4)));
typedef float f32x16 __attribute__((ext_vector_type(16)));

#define DIM   3072
#define NTOK  3200
#define NHEAD 24
#define SCALE 0.08838834764831845f   // 1/sqrt(128)
#define LOG2E 1.4426950408889634f

__device__ __forceinline__ void async16(const void* g, void* l) {
  __builtin_amdgcn_global_load_lds(
      (const __attribute__((address_space(1))) uint32_t*)g,
      (__attribute__((address_space(3))) uint32_t*)l, 16, 0, 0);
}

__device__ __forceinline__ uint32_t pkrtz(float a, float b) {
  auto p = __builtin_amdgcn_cvt_pkrtz(a, b);   // __fp16 ext_vector(2)
  return __builtin_bit_cast(uint32_t, p);
}

__device__ __forceinline__ float fexp2(float x) {   // raw v_exp_f32 (log2 domain)
  float r;
  asm("v_exp_f32 %0, %1" : "=v"(r) : "v"(x));
  return r;
}

__device__ __forceinline__ f32x4 mfma16(f16x8 a, f16x8 b, f32x4 c) {
  return __builtin_amdgcn_mfma_f32_16x16x32_f16(a, b, c, 0, 0, 0);
}

// bijective XCD-chunked remap (m204): dispatch id -> logical wgid so that
// consecutive logical ids land on the same XCD (L2 locality for shared panels).
__device__ __forceinline__ int xcd_remap(int orig, int nwg) {
  int q = nwg >> 3, r = nwg & 7;
  int xcd = orig & 7;
  int base = xcd < r ? xcd * (q + 1) : r * (q + 1) + (xcd - r) * q;
  return base + (orig >> 3);
}

// ---------------- prep kernels ----------------

__global__ __launch_bounds__(256) void cvt_f32_f16(const float* __restrict__ in,
                                                   f16* __restrict__ out) {
  size_t i = ((size_t)blockIdx.x * 256 + threadIdx.x) * 4;
  float4 v = *(const float4*)(in + i);
  f16x4 o = {(f16)v.x, (f16)v.y, (f16)v.z, (f16)v.w};
  *(f16x4*)(out + i) = o;
}

// W [3072][3072] f32 row-major -> WT [n][k] f16
__global__ __launch_bounds__(256) void transpose4(
    const float* __restrict__ W0, const float* __restrict__ W1,
    const float* __restrict__ W2, const float* __restrict__ W3,
    f16* __restrict__ T0, f16* __restrict__ T1,
    f16* __restrict__ T2, f16* __restrict__ T3) {
  const float* W; f16* T;
  switch (blockIdx.z) {
    case 0: W = W0; T = T0; break;
    case 1: W = W1; T = T1; break;
    case 2: W = W2; T = T2; break;
    default: W = W3; T = T3; break;
  }
  __shared__ float t[32][33];
  int tx = threadIdx.x & 31, ty = threadIdx.x >> 5;
  size_t bx = (size_t)blockIdx.x * 32, by = (size_t)blockIdx.y * 32;
#pragma unroll
  for (int r = 0; r < 4; ++r)
    t[ty + r * 8][tx] = W[(by + ty + r * 8) * DIM + bx + tx];
  __syncthreads();
#pragma unroll
  for (int r = 0; r < 4; ++r)
    T[(bx + ty + r * 8) * DIM + by + tx] = (f16)t[tx][ty + r * 8];
}

// 3D RoPE cos/sin tables: [3200][64] f32 each
__global__ __launch_bounds__(256) void rope_tables(float* __restrict__ cosT,
                                                   float* __restrict__ sinT) {
  int tid = blockIdx.x * 256 + threadIdx.x;  // < 3200*64
  int p = tid >> 6, j = tid & 63;
  int t = p / 400, rem = p % 400;
  int hh = rem / 20, ww = rem % 20;
  float val, e;
  if (j < 16)      { val = (float)t;  e = (float)(2 * j)        * (1.f / 32.f); }
  else if (j < 40) { val = (float)hh; e = (float)(2 * (j - 16)) * (1.f / 48.f); }
  else             { val = (float)ww; e = (float)(2 * (j - 40)) * (1.f / 48.f); }
  float f = val * expf(-e * 9.210340371976184f);  // 10000^-e
  cosT[tid] = cosf(f);
  sinT[tid] = sinf(f);
}

// ======== GEMM: 256x256 tile, BK=64, 8 waves, 4-phase counted-vmcnt pipeline ========

__device__ __forceinline__ void stage_half(const f16* __restrict__ base, int row0,
                                           int rowmax, int k0, char* ldsdst, int tid) {
#pragma unroll
  for (int s = 0; s < 2; ++s) {
    int idx = s * 512 + tid;          // 16B-chunk index, 0..1023
    int r = idx >> 3, pc = idx & 7;   // local row 0..127, physical chunk
    int cc = pc ^ (r & 7);            // logical chunk (inverse-swizzled source)
    int grow = row0 + r;
    grow = grow < rowmax ? grow : rowmax - 1;
    async16(base + (size_t)grow * DIM + k0 + cc * 8, ldsdst + idx * 16);
  }
}

__device__ __forceinline__ void gemm256_body(
    const f16* __restrict__ A, const f16* __restrict__ Bm,
    const float* __restrict__ bias, void* __restrict__ C,
    int m0, int n0, int Mrows, int mode, char* smem) {

  const int tid = threadIdx.x;
  const int lane = tid & 63, w = tid >> 6;
  const int wm = w >> 2, wn = w & 3;          // 2 x 4 wave grid
  const int l15 = lane & 15, l4 = lane >> 4;

  f32x4 acc[8][4];
#pragma unroll
  for (int m = 0; m < 8; ++m)
#pragma unroll
    for (int n = 0; n < 4; ++n) acc[m][n] = (f32x4){0.f, 0.f, 0.f, 0.f};

  const int NT = DIM / 64;  // 48

  // prologue: Ah0(0) Bh0(0) Ah1(0) Bh1(0) Ah0(1)  (10 loads/thread)
  stage_half(A,  m0,       Mrows,   0,  smem + 0,     tid);
  stage_half(Bm, n0,       1 << 30, 0,  smem + 32768, tid);
  stage_half(A,  m0 + 128, Mrows,   0,  smem + 16384, tid);
  stage_half(Bm, n0 + 128, 1 << 30, 0,  smem + 49152, tid);
  stage_half(A,  m0,       Mrows,   64, smem + 65536, tid);
  asm volatile("s_waitcnt vmcnt(2)" ::: "memory");
  __builtin_amdgcn_s_barrier();

  const int arow0 = wm * 128 + l15;
  const int brow0 = wn * 64 + l15;

  for (int t = 0; t < NT; ++t) {
    char* bufc = smem + (t & 1) * 65536;
    char* bufn = smem + ((t + 1) & 1) * 65536;
    const f16* Ald = (const f16*)bufc;
    const f16* Bld = (const f16*)(bufc + 32768);
    int k1 = (t + 1) * 64; k1 = k1 <= DIM - 64 ? k1 : DIM - 64;  // tail clamp
    int k2 = (t + 2) * 64; k2 = k2 <= DIM - 64 ? k2 : DIM - 64;

    f16x8 af[8], b0, b1;

    // ---- phase 0 ----
#pragma unroll
    for (int m = 0; m < 8; ++m) {
      int r = arow0 + m * 16, pc = l4 ^ (r & 7);
      af[m] = *(const f16x8*)(Ald + r * 64 + pc * 8);
    }
    { int r = brow0,      pc = l4 ^ (r & 7); b0 = *(const f16x8*)(Bld + r * 64 + pc * 8);
      r = brow0 + 16;     pc = l4 ^ (r & 7); b1 = *(const f16x8*)(Bld + r * 64 + pc * 8); }
    stage_half(Bm, n0, 1 << 30, k1, bufn + 32768, tid);
    __builtin_amdgcn_s_barrier();
    asm volatile("s_waitcnt lgkmcnt(0)" ::: "memory");
    __builtin_amdgcn_sched_barrier(0);
    __builtin_amdgcn_s_setprio(1);
#pragma unroll
    for (int m = 0; m < 8; ++m) {
      acc[m][0] = mfma16(af[m], b0, acc[m][0]);
      acc[m][1] = mfma16(af[m], b1, acc[m][1]);
    }
    __builtin_amdgcn_s_setprio(0);
    __builtin_amdgcn_s_barrier();

    // ---- phase 1 ----
    { int r = brow0 + 32, pc = l4 ^ (r & 7); b0 = *(const f16x8*)(Bld + r * 64 + pc * 8);
      r = brow0 + 48;     pc = l4 ^ (r & 7); b1 = *(const f16x8*)(Bld + r * 64 + pc * 8); }
    stage_half(A, m0 + 128, Mrows, k1, bufn + 16384, tid);
    __builtin_amdgcn_s_barrier();
    asm volatile("s_waitcnt lgkmcnt(0)" ::: "memory");
    __builtin_amdgcn_sched_barrier(0);
    __builtin_amdgcn_s_setprio(1);
#pragma unroll
    for (int m = 0; m < 8; ++m) {
      acc[m][2] = mfma16(af[m], b0, acc[m][2]);
      acc[m][3] = mfma16(af[m], b1, acc[m][3]);
    }
    __builtin_amdgcn_s_setprio(0);
    __builtin_amdgcn_s_barrier();

    // ---- phase 2 ----
#pragma unroll
    for (int m = 0; m < 8; ++m) {
      int r = arow0 + m * 16, pc = (4 + l4) ^ (r & 7);
      af[m] = *(const f16x8*)(Ald + r * 64 + pc * 8);
    }
    { int r = brow0,      pc = (4 + l4) ^ (r & 7); b0 = *(const f16x8*)(Bld + r * 64 + pc * 8);
      r = brow0 + 16;     pc = (4 + l4) ^ (r & 7); b1 = *(const f16x8*)(Bld + r * 64 + pc * 8); }
    stage_half(Bm, n0 + 128, 1 << 30, k1, bufn + 49152, tid);
    __builtin_amdgcn_s_barrier();
    asm volatile("s_waitcnt lgkmcnt(0)" ::: "memory");
    __builtin_amdgcn_sched_barrier(0);
    __builtin_amdgcn_s_setprio(1);
#pragma unroll
    for (int m = 0; m < 8; ++m) {
      acc[m][0] = mfma16(af[m], b0, acc[m][0]);
      acc[m][1] = mfma16(af[m], b1, acc[m][1]);
    }
    __builtin_amdgcn_s_setprio(0);
    __builtin_amdgcn_s_barrier();

    // ---- phase 3 ----
    { int r = brow0 + 32, pc = (4 + l4) ^ (r & 7); b0 = *(const f16x8*)(Bld + r * 64 + pc * 8);
      r = brow0 + 48;     pc = (4 + l4) ^ (r & 7); b1 = *(const f16x8*)(Bld + r * 64 + pc * 8); }
    stage_half(A, m0, Mrows, k2, bufc + 0, tid);   // A-reads of tile t done at ph2
    __builtin_amdgcn_s_barrier();
    asm volatile("s_waitcnt lgkmcnt(0)" ::: "memory");
    __builtin_amdgcn_sched_barrier(0);
    __builtin_amdgcn_s_setprio(1);
#pragma unroll
    for (int m = 0; m < 8; ++m) {
      acc[m][2] = mfma16(af[m], b0, acc[m][2]);
      acc[m][3] = mfma16(af[m], b1, acc[m][3]);
    }
    __builtin_amdgcn_s_setprio(0);
    asm volatile("s_waitcnt vmcnt(2)" ::: "memory");   // tile t+1 landed; Ah0(t+2) in flight
    __builtin_amdgcn_s_barrier();
  }

  // epilogue: C/D layout col=lane&15, row=(lane>>4)*4+r
#pragma unroll
  for (int n = 0; n < 4; ++n) {
    int col = n0 + wn * 64 + n * 16 + l15;
    float bb = bias[col];
#pragma unroll
    for (int m = 0; m < 8; ++m) {
      int rbase = m0 + wm * 128 + m * 16 + l4 * 4;
      if (rbase < Mrows) {
        if (mode == 2) {            // vt[col][kv] : [3072][3200]
          f16x4 ov;
#pragma unroll
          for (int r = 0; r < 4; ++r) ov[r] = (f16)(acc[m][n][r] + bb);
          *(f16x4*)((f16*)C + (size_t)col * NTOK + rbase) = ov;
        } else if (mode == 1) {
#pragma unroll
          for (int r = 0; r < 4; ++r)
            ((float*)C)[(size_t)(rbase + r) * DIM + col] = acc[m][n][r] + bb;
        } else {
#pragma unroll
          for (int r = 0; r < 4; ++r)
            ((f16*)C)[(size_t)(rbase + r) * DIM + col] = (f16)(acc[m][n][r] + bb);
        }
      }
    }
  }
}

__global__ __launch_bounds__(512, 2) void gemm256_qkv(
    const f16* __restrict__ A,
    const f16* __restrict__ B0, const f16* __restrict__ B1, const f16* __restrict__ B2,
    const float* __restrict__ b0, const float* __restrict__ b1, const float* __restrict__ b2,
    f16* __restrict__ C0, f16* __restrict__ C1, f16* __restrict__ C2) {
  __shared__ char smem[131072];
  // XCD-chunked remap over 468 blocks (13 m-tiles x 36 y): same-y groups
  // (13 consecutive wgids sharing one 1.5MB B panel) land on one XCD.
  int wgid = xcd_remap(blockIdx.y * 13 + blockIdx.x, 13 * 36);
  int mt = wgid % 13, yy = wgid / 13;
  int sel = yy / 12, yn = yy % 12;
  const f16* B = sel == 0 ? B0 : (sel == 1 ? B1 : B2);
  const float* bias = sel == 0 ? b0 : (sel == 1 ? b1 : b2);
  f16* C = sel == 0 ? C0 : (sel == 1 ? C1 : C2);
  gemm256_body(A, B, bias, C, mt * 256, yn * 256, NTOK, sel == 2 ? 2 : 0, smem);
}

__global__ __launch_bounds__(512, 2) void gemm256_out(
    const f16* __restrict__ A, const f16* __restrict__ B,
    const float* __restrict__ bias, float* __restrict__ C) {
  __shared__ char smem[131072];
  int wgid = xcd_remap(blockIdx.y * 13 + blockIdx.x, 13 * 12);
  int mt = wgid % 13, ny = wgid / 13;
  gemm256_body(A, B, bias, C, mt * 256, ny * 256, NTOK, 1, smem);
}

// ---------------- fused rmsnorm + rope (q and k in one launch) ----------------
__global__ __launch_bounds__(256) void rmsnorm_rope2(
    f16* __restrict__ qbuf, f16* __restrict__ kbuf,
    const float* __restrict__ qw, const float* __restrict__ kw,
    const float* __restrict__ cosT, const float* __restrict__ sinT) {
  f16* qk = blockIdx.y ? kbuf : qbuf;
  const float* w = blockIdx.y ? kw : qw;
  const float osc = blockIdx.y ? 1.0f : SCALE * LOG2E;   // q pre-scaled to log2 domain
  int lane = threadIdx.x & 63, rb = threadIdx.x >> 6;
  int row = blockIdx.x * 4 + rb;   // token*24 + head
  int p = row / NHEAD;             // token
  f16* ptr = qk + (size_t)row * 128 + lane * 2;
  f16x2 hv = *(const f16x2*)ptr;
  float x1 = (float)hv[0], x2 = (float)hv[1];
  float ss = x1 * x1 + x2 * x2;
#pragma unroll
  for (int o = 32; o > 0; o >>= 1) ss += __shfl_xor(ss, o);
  float r = rsqrtf(ss * (1.f / 128.f) + 1e-6f);
  float n1 = x1 * r * w[lane * 2], n2 = x2 * r * w[lane * 2 + 1];
  float c = cosT[p * 64 + lane], s = sinT[p * 64 + lane];
  f16x2 ov = {(f16)((n1 * c - n2 * s) * osc), (f16)((n1 * s + n2 * c) * osc)};
  *(f16x2*)ptr = ov;
}

// ---------------- flash attention v12: drop V-staging (L2-resident), K-only LDS ----------------
// Grid 840 = 720 noise half-blocks (kv 0..1664 / 1664..3200) + 120 cond (kv 0..800).
// Per XCD 3 heads -> K+V working set ~4.9MB ~ L2. V^T read DIRECTLY from global
// in PV (m169 precedent: stage only what doesn't cache-fit). LDS = K only (32KB)
// -> 3 blocks/CU (15 waves, was 10). K(t+1) staged right after QK(t) behind a raw
// s_barrier (softmax+PV hide it); end-of-loop __syncthreads drains. Same 2
// barriers/tile as before, zero exposed staging drain, single K buffer.
__global__ __launch_bounds__(320) void attn12(
    const f16* __restrict__ q, const f16* __restrict__ k, const f16* __restrict__ vt,
    f16* __restrict__ out, f16* __restrict__ Op, float2* __restrict__ ml) {
  __shared__ char smem[32768];
  f16* Ks = (f16*)smem;            // [128 kv][128 d] chunk-swizzled (^ row&15)

  // XCD-chunked remap: 840 = 8 XCD x 105; per XCD 3 heads x (30 noise-halves + 5 cond)
  int L = blockIdx.x;
  int xcd = L & 7, j = L >> 3;         // j 0..104
  int head = xcd * 3 + j / 35;
  int u = j % 35;
  int q0, kv_lo, kv_hi, s = 0;
  bool direct;
  if (u < 30) {                        // noise half (tile-aligned split 13/12 tiles)
    int qn = u >> 1; s = u & 1;
    q0 = 800 + qn * 160;
    kv_lo = s ? 1664 : 0;
    kv_hi = s ? 3200 : 1664;
    direct = false;
  } else {                             // cond (short; dispatched last in head-group)
    q0 = (u - 30) * 160; kv_lo = 0; kv_hi = 800; direct = true;
  }

  const int tid = threadIdx.x, lane = tid & 63, w = tid >> 6;
  const int l31 = lane & 31, hi = lane >> 5;
  const int qg = q0 + w * 32 + l31;
  const int sw_base = l31 & 15;

  // Q frags (B-side): lane q=l31, d = ks*16 + hi*8 + e (pre-scaled by SCALE*log2e)
  f16x8 qr[8];
#pragma unroll
  for (int ks = 0; ks < 8; ++ks)
    qr[ks] = *(const f16x8*)(q + (size_t)qg * DIM + head * 128 + ks * 16 + hi * 8);

  // V^T row base (global, L2-resident): PV A-operand row for mb: +mb*32*NTOK
  const f16* vrow0 = vt + ((size_t)head * 128 + l31) * NTOK;

  const f16x8 ones = {(f16)1, (f16)1, (f16)1, (f16)1, (f16)1, (f16)1, (f16)1, (f16)1};

  f32x16 o[4], lsum;
#pragma unroll
  for (int mb = 0; mb < 4; ++mb)
#pragma unroll
    for (int r = 0; r < 16; ++r) o[mb][r] = 0.f;
#pragma unroll
  for (int r = 0; r < 16; ++r) lsum[r] = 0.f;
  float m_run = -1e30f;

  // prologue: stage K(kv_lo) (2048 16B chunks, chunk-XOR swizzle c^(row&15))
#pragma unroll
  for (int r = 0; r < 7; ++r) {
    int idx = r * 320 + tid;
    if (idx < 2048) {
      int row = idx >> 4;
      int sw = (idx & 15) ^ (row & 15);
      async16(k + (size_t)(kv_lo + row) * DIM + head * 128 + sw * 8, smem + idx * 16);
    }
  }
  __syncthreads();

  for (int t0 = kv_lo; t0 < kv_hi; t0 += 128) {
    const int nvb = min(4, (kv_hi - t0) >> 5);   // valid 32-kv blocks (>=1)

    // S^T = K . Q^T : D[m=kv][n=q]; lane q=l31
    f32x16 s4[4];
#pragma unroll
    for (int b = 0; b < 4; ++b)
#pragma unroll
      for (int r = 0; r < 16; ++r) s4[b][r] = 0.f;
    __builtin_amdgcn_s_setprio(1);
#pragma unroll
    for (int ks = 0; ks < 8; ++ks) {
#pragma unroll
      for (int b = 0; b < 4; ++b) {
        if (b < nvb) {
          const f16x8 kf = *(const f16x8*)(Ks + ((b * 32 + l31) << 7) +
                                           (((ks * 2 + hi) ^ sw_base) << 3));
          s4[b] = __builtin_amdgcn_mfma_f32_32x32x16_f16(kf, qr[ks], s4[b], 0, 0, 0);
        }
      }
    }
    __builtin_amdgcn_s_setprio(0);

    __builtin_amdgcn_s_barrier();   // all waves done QK reads of Ks(t)

    // stage K(t+1) now; flies under softmax+PV; drained by end __syncthreads
    if (t0 + 128 < kv_hi) {
      const int tn = t0 + 128;
#pragma unroll
      for (int r = 0; r < 7; ++r) {
        int idx = r * 320 + tid;
        if (idx < 2048) {
          int row = idx >> 4;
          int sw = (idx & 15) ^ (row & 15);
          async16(k + (size_t)(tn + row) * DIM + head * 128 + sw * 8, smem + idx * 16);
        }
      }
    }

    // tile max + defer-max (single check, log2 domain)
    float tmax = -1e30f;
#pragma unroll
    for (int b = 0; b < 4; ++b)
      if (b < nvb)
#pragma unroll
        for (int r = 0; r < 16; r += 2)
          tmax = fmaxf(tmax, fmaxf(s4[b][r], s4[b][r + 1]));
    tmax = fmaxf(tmax, __shfl_xor(tmax, 32));
    if (!__all(tmax <= m_run + 11.54f)) {          // defer-max (T13), 8 nat in bits
      float mn = fmaxf(m_run, tmax);
      float alpha = fexp2(m_run - mn);
#pragma unroll
      for (int mb = 0; mb < 4; ++mb)
#pragma unroll
        for (int r = 0; r < 16; ++r) o[mb][r] *= alpha;
#pragma unroll
      for (int r = 0; r < 16; ++r) lsum[r] *= alpha;
      m_run = mn;
    }

    // exp b=0 up front; exp b+1 interleaved into b's PV (hides under MFMA)
#pragma unroll
    for (int r = 0; r < 16; ++r) s4[0][r] = fexp2(s4[0][r] - m_run);

    const int nks = nvb * 2;
    __builtin_amdgcn_s_setprio(1);
#pragma unroll
    for (int ks = 0; ks < 8; ++ks) {
      if (ks < nks) {
        const int b = ks >> 1, s8 = (ks & 1) * 8;
        if ((ks & 1) && (b + 1) < nvb) {
#pragma unroll
          for (int r = 0; r < 16; ++r)
            s4[b + 1][r] = fexp2(s4[b + 1][r] - m_run);
        }
        uint32_t a0 = pkrtz(s4[b][s8 + 0], s4[b][s8 + 1]);
        uint32_t b0 = pkrtz(s4[b][s8 + 4], s4[b][s8 + 5]);
        asm("v_permlane32_swap_b32 %0, %1" : "+v"(a0), "+v"(b0));
        uint32_t a1 = pkrtz(s4[b][s8 + 2], s4[b][s8 + 3]);
        uint32_t b1 = pkrtz(s4[b][s8 + 6], s4[b][s8 + 7]);
        asm("v_permlane32_swap_b32 %0, %1" : "+v"(a1), "+v"(b1));
        union { uint32_t u[4]; f16x8 v; } pf2;
        pf2.u[0] = a0; pf2.u[1] = a1; pf2.u[2] = b0; pf2.u[3] = b1;
#pragma unroll
        for (int mb = 0; mb < 4; ++mb) {
          // V^T direct from global/L2: row = head*128 + mb*32 + l31, col = t0 + chunk*8
          const f16x8 vf = *(const f16x8*)(vrow0 + (size_t)mb * 32 * NTOK +
                                           t0 + (ks * 2 + hi) * 8);
          o[mb] = __builtin_amdgcn_mfma_f32_32x32x16_f16(vf, pf2.v, o[mb], 0, 0, 0);
        }
        lsum = __builtin_amdgcn_mfma_f32_32x32x16_f16(ones, pf2.v, lsum, 0, 0, 0);
      }
    }
    __builtin_amdgcn_s_setprio(0);

    __syncthreads();   // drains own vmcnt -> K(t+1) landed; all waves synced
  }

  float inv = 1.f / lsum[0];
  // O^T: lane q=l31; d = mb*32 + (r&3) + 8*(r>>2) + 4*hi
  f16* obase = direct
      ? out + (size_t)qg * DIM + head * 128
      : Op + ((size_t)(s * NHEAD + head) * 2400 + (qg - 800)) * 128;
#pragma unroll
  for (int mb = 0; mb < 4; ++mb)
#pragma unroll
    for (int jq = 0; jq < 4; ++jq) {
      f16x4 ov;
#pragma unroll
      for (int e = 0; e < 4; ++e) ov[e] = (f16)(o[mb][jq * 4 + e] * inv);
      *(f16x4*)(obase + mb * 32 + jq * 8 + hi * 4) = ov;
    }
  if (!direct && hi == 0)
    ml[(size_t)(s * NHEAD + head) * 2400 + (qg - 800)] = make_float2(m_run, lsum[0]);
}

// ---------------- merge of the two noise kv-halves ----------------
// out[800+qn][head*128+d] = (O1*w1 + O2*w2)/(w1+w2), w_s = l_s * 2^(m_s - m)
__global__ __launch_bounds__(256) void attn_merge(
    const f16* __restrict__ Op, const float2* __restrict__ ml,
    f16* __restrict__ out) {
  int row = blockIdx.x * 4 + (threadIdx.x >> 6);   // 0..57599 = head*2400 + qn
  int lane = threadIdx.x & 63;
  int head = row / 2400, qn = row % 2400;
  float2 ml1 = ml[row];
  float2 ml2 = ml[24 * 2400 + row];
  float m = fmaxf(ml1.x, ml2.x);
  float w1 = ml1.y * fexp2(ml1.x - m);
  float w2 = ml2.y * fexp2(ml2.x - m);
  float inv = 1.f / (w1 + w2);
  w1 *= inv; w2 *= inv;
  f16x2 o1 = *(const f16x2*)(Op + (size_t)row * 128 + lane * 2);
  f16x2 o2 = *(const f16x2*)(Op + (size_t)(24 * 2400 + row) * 128 + lane * 2);
  f16x2 ov = {(f16)((float)o1[0] * w1 + (float)o2[0] * w2),
              (f16)((float)o1[1] * w1 + (float)o2[1] * w2)};
  *(f16x2*)(out + (size_t)(800 + qn) * DIM + head * 128 + lane * 2) = ov;
}

// ---------------- launcher ----------------

extern "C" void kernel_launch(void* const* d_in, const int* in_sizes, int n_in,
                              void* d_out, int out_size, void* d_ws, size_t ws_size,
                              hipStream_t stream) {
  const float* x   = (const float*)d_in[0];
  const float* Wq  = (const float*)d_in[1];
  const float* bq  = (const float*)d_in[2];
  const float* Wk  = (const float*)d_in[3];
  const float* bk  = (const float*)d_in[4];
  const float* Wv  = (const float*)d_in[5];
  const float* bv  = (const float*)d_in[6];
  const float* Wo  = (const float*)d_in[7];
  const float* bo  = (const float*)d_in[8];
  const float* qnw = (const float*)d_in[9];
  const float* knw = (const float*)d_in[10];
  // d_in[11] = num_cond_latents: fixed 2 per setup -> nct = 800 (grid geometry)

  char* ws = (char*)d_ws;
  f16*   xb   = (f16*)(ws);                       // 19,660,800 B
  f16*   WqT  = (f16*)(ws + 19660800);            // 18,874,368 B each
  f16*   WkT  = (f16*)(ws + 38535168);
  f16*   WvT  = (f16*)(ws + 57409536);
  f16*   WoT  = (f16*)(ws + 76283904);
  f16*   qb   = (f16*)(ws + 95158272);            // 19,660,800 B each
  f16*   kb   = (f16*)(ws + 114819072);
  f16*   vtb  = (f16*)(ws + 134479872);           // V^T [3072][3200]
  f16*   ab   = (f16*)(ws + 154140672);
  float* cosT = (float*)(ws + 173801472);         // 819,200 B each
  float* sinT = (float*)(ws + 174620672);         // end: 175,439,872 B
  // attn partials: reuse xb/WqT region (dead after gemm256_qkv)
  f16*    Op  = (f16*)(ws);                       // [2][24][2400][128] f16 = 29,491,200 B
  float2* ml  = (float2*)(ws + 29491200);         // [2][24][2400] float2 = 921,600 B

  cvt_f32_f16<<<9600, 256, 0, stream>>>(x, xb);
  transpose4<<<dim3(96, 96, 4), 256, 0, stream>>>(Wq, Wk, Wv, Wo, WqT, WkT, WvT, WoT);
  rope_tables<<<800, 256, 0, stream>>>(cosT, sinT);

  gemm256_qkv<<<dim3(13, 36), 512, 0, stream>>>(xb, WqT, WkT, WvT, bq, bk, bv, qb, kb, vtb);

  rmsnorm_rope2<<<dim3(19200, 2), 256, 0, stream>>>(qb, kb, qnw, knw, cosT, sinT);

  attn12<<<840, 320, 0, stream>>>(qb, kb, vtb, ab, Op, ml);
  attn_merge<<<14400, 256, 0, stream>>>(Op, ml, ab);

  gemm256_out<<<dim3(13, 12), 512, 0, stream>>>(ab, WoT, bo, (float*)d_out);
}

// Round 16
// 536.066 us; speedup vs baseline: 1.2193x; 1.2193x over previous
//
#include <hip/hip_runtime.h>
#include <stdint.h>

typedef _Float16 f16;
typedef _Float16 f16x2 __attribute__((ext_vector_type(2)));
typedef _Float16 f16x4 __attribute__((ext_vector_type(4)));
typedef _Float16 f16x8 __attribute__((ext_vector_type(8)));
typedef float f32x4 __attribute__((ext_vector_type(4)));
typedef float f32x16 __attribute__((ext_vector_type(16)));

#define DIM   3072
#define NTOK  3200
#define NHEAD 24
#define SCALE 0.08838834764831845f   // 1/sqrt(128)
#define LOG2E 1.4426950408889634f

__device__ __forceinline__ void async16(const void* g, void* l) {
  __builtin_amdgcn_global_load_lds(
      (const __attribute__((address_space(1))) uint32_t*)g,
      (__attribute__((address_space(3))) uint32_t*)l, 16, 0, 0);
}

__device__ __forceinline__ uint32_t pkrtz(float a, float b) {
  auto p = __builtin_amdgcn_cvt_pkrtz(a, b);   // __fp16 ext_vector(2)
  return __builtin_bit_cast(uint32_t, p);
}

__device__ __forceinline__ float fexp2(float x) {   // raw v_exp_f32 (log2 domain)
  float r;
  asm("v_exp_f32 %0, %1" : "=v"(r) : "v"(x));
  return r;
}

__device__ __forceinline__ f32x4 mfma16(f16x8 a, f16x8 b, f32x4 c) {
  return __builtin_amdgcn_mfma_f32_16x16x32_f16(a, b, c, 0, 0, 0);
}

// bijective XCD-chunked remap (m204): dispatch id -> logical wgid so that
// consecutive logical ids land on the same XCD (L2 locality for shared panels).
__device__ __forceinline__ int xcd_remap(int orig, int nwg) {
  int q = nwg >> 3, r = nwg & 7;
  int xcd = orig & 7;
  int base = xcd < r ? xcd * (q + 1) : r * (q + 1) + (xcd - r) * q;
  return base + (orig >> 3);
}

// ---------------- prep kernels ----------------

__global__ __launch_bounds__(256) void cvt_f32_f16(const float* __restrict__ in,
                                                   f16* __restrict__ out) {
  size_t i = ((size_t)blockIdx.x * 256 + threadIdx.x) * 4;
  float4 v = *(const float4*)(in + i);
  f16x4 o = {(f16)v.x, (f16)v.y, (f16)v.z, (f16)v.w};
  *(f16x4*)(out + i) = o;
}

// W [3072][3072] f32 row-major -> WT [n][k] f16
__global__ __launch_bounds__(256) void transpose4(
    const float* __restrict__ W0, const float* __restrict__ W1,
    const float* __restrict__ W2, const float* __restrict__ W3,
    f16* __restrict__ T0, f16* __restrict__ T1,
    f16* __restrict__ T2, f16* __restrict__ T3) {
  const float* W; f16* T;
  switch (blockIdx.z) {
    case 0: W = W0; T = T0; break;
    case 1: W = W1; T = T1; break;
    case 2: W = W2; T = T2; break;
    default: W = W3; T = T3; break;
  }
  __shared__ float t[32][33];
  int tx = threadIdx.x & 31, ty = threadIdx.x >> 5;
  size_t bx = (size_t)blockIdx.x * 32, by = (size_t)blockIdx.y * 32;
#pragma unroll
  for (int r = 0; r < 4; ++r)
    t[ty + r * 8][tx] = W[(by + ty + r * 8) * DIM + bx + tx];
  __syncthreads();
#pragma unroll
  for (int r = 0; r < 4; ++r)
    T[(bx + ty + r * 8) * DIM + by + tx] = (f16)t[tx][ty + r * 8];
}

// 3D RoPE cos/sin tables: [3200][64] f32 each
__global__ __launch_bounds__(256) void rope_tables(float* __restrict__ cosT,
                                                   float* __restrict__ sinT) {
  int tid = blockIdx.x * 256 + threadIdx.x;  // < 3200*64
  int p = tid >> 6, j = tid & 63;
  int t = p / 400, rem = p % 400;
  int hh = rem / 20, ww = rem % 20;
  float val, e;
  if (j < 16)      { val = (float)t;  e = (float)(2 * j)        * (1.f / 32.f); }
  else if (j < 40) { val = (float)hh; e = (float)(2 * (j - 16)) * (1.f / 48.f); }
  else             { val = (float)ww; e = (float)(2 * (j - 40)) * (1.f / 48.f); }
  float f = val * expf(-e * 9.210340371976184f);  // 10000^-e
  cosT[tid] = cosf(f);
  sinT[tid] = sinf(f);
}

// ======== GEMM: 256x256 tile, BK=64, 8 waves, 4-phase counted-vmcnt pipeline ========

__device__ __forceinline__ void stage_half(const f16* __restrict__ base, int row0,
                                           int rowmax, int k0, char* ldsdst, int tid) {
#pragma unroll
  for (int s = 0; s < 2; ++s) {
    int idx = s * 512 + tid;          // 16B-chunk index, 0..1023
    int r = idx >> 3, pc = idx & 7;   // local row 0..127, physical chunk
    int cc = pc ^ (r & 7);            // logical chunk (inverse-swizzled source)
    int grow = row0 + r;
    grow = grow < rowmax ? grow : rowmax - 1;
    async16(base + (size_t)grow * DIM + k0 + cc * 8, ldsdst + idx * 16);
  }
}

__device__ __forceinline__ void gemm256_body(
    const f16* __restrict__ A, const f16* __restrict__ Bm,
    const float* __restrict__ bias, void* __restrict__ C,
    int m0, int n0, int Mrows, int mode, char* smem) {

  const int tid = threadIdx.x;
  const int lane = tid & 63, w = tid >> 6;
  const int wm = w >> 2, wn = w & 3;          // 2 x 4 wave grid
  const int l15 = lane & 15, l4 = lane >> 4;

  f32x4 acc[8][4];
#pragma unroll
  for (int m = 0; m < 8; ++m)
#pragma unroll
    for (int n = 0; n < 4; ++n) acc[m][n] = (f32x4){0.f, 0.f, 0.f, 0.f};

  const int NT = DIM / 64;  // 48

  // prologue: Ah0(0) Bh0(0) Ah1(0) Bh1(0) Ah0(1)  (10 loads/thread)
  stage_half(A,  m0,       Mrows,   0,  smem + 0,     tid);
  stage_half(Bm, n0,       1 << 30, 0,  smem + 32768, tid);
  stage_half(A,  m0 + 128, Mrows,   0,  smem + 16384, tid);
  stage_half(Bm, n0 + 128, 1 << 30, 0,  smem + 49152, tid);
  stage_half(A,  m0,       Mrows,   64, smem + 65536, tid);
  asm volatile("s_waitcnt vmcnt(2)" ::: "memory");
  __builtin_amdgcn_s_barrier();

  const int arow0 = wm * 128 + l15;
  const int brow0 = wn * 64 + l15;

  for (int t = 0; t < NT; ++t) {
    char* bufc = smem + (t & 1) * 65536;
    char* bufn = smem + ((t + 1) & 1) * 65536;
    const f16* Ald = (const f16*)bufc;
    const f16* Bld = (const f16*)(bufc + 32768);
    int k1 = (t + 1) * 64; k1 = k1 <= DIM - 64 ? k1 : DIM - 64;  // tail clamp
    int k2 = (t + 2) * 64; k2 = k2 <= DIM - 64 ? k2 : DIM - 64;

    f16x8 af[8], b0, b1;

    // ---- phase 0 ----
#pragma unroll
    for (int m = 0; m < 8; ++m) {
      int r = arow0 + m * 16, pc = l4 ^ (r & 7);
      af[m] = *(const f16x8*)(Ald + r * 64 + pc * 8);
    }
    { int r = brow0,      pc = l4 ^ (r & 7); b0 = *(const f16x8*)(Bld + r * 64 + pc * 8);
      r = brow0 + 16;     pc = l4 ^ (r & 7); b1 = *(const f16x8*)(Bld + r * 64 + pc * 8); }
    stage_half(Bm, n0, 1 << 30, k1, bufn + 32768, tid);
    __builtin_amdgcn_s_barrier();
    asm volatile("s_waitcnt lgkmcnt(0)" ::: "memory");
    __builtin_amdgcn_sched_barrier(0);
    __builtin_amdgcn_s_setprio(1);
#pragma unroll
    for (int m = 0; m < 8; ++m) {
      acc[m][0] = mfma16(af[m], b0, acc[m][0]);
      acc[m][1] = mfma16(af[m], b1, acc[m][1]);
    }
    __builtin_amdgcn_s_setprio(0);
    __builtin_amdgcn_s_barrier();

    // ---- phase 1 ----
    { int r = brow0 + 32, pc = l4 ^ (r & 7); b0 = *(const f16x8*)(Bld + r * 64 + pc * 8);
      r = brow0 + 48;     pc = l4 ^ (r & 7); b1 = *(const f16x8*)(Bld + r * 64 + pc * 8); }
    stage_half(A, m0 + 128, Mrows, k1, bufn + 16384, tid);
    __builtin_amdgcn_s_barrier();
    asm volatile("s_waitcnt lgkmcnt(0)" ::: "memory");
    __builtin_amdgcn_sched_barrier(0);
    __builtin_amdgcn_s_setprio(1);
#pragma unroll
    for (int m = 0; m < 8; ++m) {
      acc[m][2] = mfma16(af[m], b0, acc[m][2]);
      acc[m][3] = mfma16(af[m], b1, acc[m][3]);
    }
    __builtin_amdgcn_s_setprio(0);
    __builtin_amdgcn_s_barrier();

    // ---- phase 2 ----
#pragma unroll
    for (int m = 0; m < 8; ++m) {
      int r = arow0 + m * 16, pc = (4 + l4) ^ (r & 7);
      af[m] = *(const f16x8*)(Ald + r * 64 + pc * 8);
    }
    { int r = brow0,      pc = (4 + l4) ^ (r & 7); b0 = *(const f16x8*)(Bld + r * 64 + pc * 8);
      r = brow0 + 16;     pc = (4 + l4) ^ (r & 7); b1 = *(const f16x8*)(Bld + r * 64 + pc * 8); }
    stage_half(Bm, n0 + 128, 1 << 30, k1, bufn + 49152, tid);
    __builtin_amdgcn_s_barrier();
    asm volatile("s_waitcnt lgkmcnt(0)" ::: "memory");
    __builtin_amdgcn_sched_barrier(0);
    __builtin_amdgcn_s_setprio(1);
#pragma unroll
    for (int m = 0; m < 8; ++m) {
      acc[m][0] = mfma16(af[m], b0, acc[m][0]);
      acc[m][1] = mfma16(af[m], b1, acc[m][1]);
    }
    __builtin_amdgcn_s_setprio(0);
    __builtin_amdgcn_s_barrier();

    // ---- phase 3 ----
    { int r = brow0 + 32, pc = (4 + l4) ^ (r & 7); b0 = *(const f16x8*)(Bld + r * 64 + pc * 8);
      r = brow0 + 48;     pc = (4 + l4) ^ (r & 7); b1 = *(const f16x8*)(Bld + r * 64 + pc * 8); }
    stage_half(A, m0, Mrows, k2, bufc + 0, tid);   // A-reads of tile t done at ph2
    __builtin_amdgcn_s_barrier();
    asm volatile("s_waitcnt lgkmcnt(0)" ::: "memory");
    __builtin_amdgcn_sched_barrier(0);
    __builtin_amdgcn_s_setprio(1);
#pragma unroll
    for (int m = 0; m < 8; ++m) {
      acc[m][2] = mfma16(af[m], b0, acc[m][2]);
      acc[m][3] = mfma16(af[m], b1, acc[m][3]);
    }
    __builtin_amdgcn_s_setprio(0);
    asm volatile("s_waitcnt vmcnt(2)" ::: "memory");   // tile t+1 landed; Ah0(t+2) in flight
    __builtin_amdgcn_s_barrier();
  }

  // epilogue: C/D layout col=lane&15, row=(lane>>4)*4+r
#pragma unroll
  for (int n = 0; n < 4; ++n) {
    int col = n0 + wn * 64 + n * 16 + l15;
    float bb = bias[col];
#pragma unroll
    for (int m = 0; m < 8; ++m) {
      int rbase = m0 + wm * 128 + m * 16 + l4 * 4;
      if (rbase < Mrows) {
        if (mode == 2) {            // vt[col][kv] : [3072][3200]
          f16x4 ov;
#pragma unroll
          for (int r = 0; r < 4; ++r) ov[r] = (f16)(acc[m][n][r] + bb);
          *(f16x4*)((f16*)C + (size_t)col * NTOK + rbase) = ov;
        } else if (mode == 1) {
#pragma unroll
          for (int r = 0; r < 4; ++r)
            ((float*)C)[(size_t)(rbase + r) * DIM + col] = acc[m][n][r] + bb;
        } else {
#pragma unroll
          for (int r = 0; r < 4; ++r)
            ((f16*)C)[(size_t)(rbase + r) * DIM + col] = (f16)(acc[m][n][r] + bb);
        }
      }
    }
  }
}

__global__ __launch_bounds__(512, 2) void gemm256_qkv(
    const f16* __restrict__ A,
    const f16* __restrict__ B0, const f16* __restrict__ B1, const f16* __restrict__ B2,
    const float* __restrict__ b0, const float* __restrict__ b1, const float* __restrict__ b2,
    f16* __restrict__ C0, f16* __restrict__ C1, f16* __restrict__ C2) {
  __shared__ char smem[131072];
  // XCD-chunked remap over 468 blocks (13 m-tiles x 36 y): same-y groups
  // (13 consecutive wgids sharing one 1.5MB B panel) land on one XCD.
  int wgid = xcd_remap(blockIdx.y * 13 + blockIdx.x, 13 * 36);
  int mt = wgid % 13, yy = wgid / 13;
  int sel = yy / 12, yn = yy % 12;
  const f16* B = sel == 0 ? B0 : (sel == 1 ? B1 : B2);
  const float* bias = sel == 0 ? b0 : (sel == 1 ? b1 : b2);
  f16* C = sel == 0 ? C0 : (sel == 1 ? C1 : C2);
  gemm256_body(A, B, bias, C, mt * 256, yn * 256, NTOK, sel == 2 ? 2 : 0, smem);
}

__global__ __launch_bounds__(512, 2) void gemm256_out(
    const f16* __restrict__ A, const f16* __restrict__ B,
    const float* __restrict__ bias, float* __restrict__ C) {
  __shared__ char smem[131072];
  int wgid = xcd_remap(blockIdx.y * 13 + blockIdx.x, 13 * 12);
  int mt = wgid % 13, ny = wgid / 13;
  gemm256_body(A, B, bias, C, mt * 256, ny * 256, NTOK, 1, smem);
}

// ---------------- fused rmsnorm + rope (q and k in one launch) ----------------
__global__ __launch_bounds__(256) void rmsnorm_rope2(
    f16* __restrict__ qbuf, f16* __restrict__ kbuf,
    const float* __restrict__ qw, const float* __restrict__ kw,
    const float* __restrict__ cosT, const float* __restrict__ sinT) {
  f16* qk = blockIdx.y ? kbuf : qbuf;
  const float* w = blockIdx.y ? kw : qw;
  const float osc = blockIdx.y ? 1.0f : SCALE * LOG2E;   // q pre-scaled to log2 domain
  int lane = threadIdx.x & 63, rb = threadIdx.x >> 6;
  int row = blockIdx.x * 4 + rb;   // token*24 + head
  int p = row / NHEAD;             // token
  f16* ptr = qk + (size_t)row * 128 + lane * 2;
  f16x2 hv = *(const f16x2*)ptr;
  float x1 = (float)hv[0], x2 = (float)hv[1];
  float ss = x1 * x1 + x2 * x2;
#pragma unroll
  for (int o = 32; o > 0; o >>= 1) ss += __shfl_xor(ss, o);
  float r = rsqrtf(ss * (1.f / 128.f) + 1e-6f);
  float n1 = x1 * r * w[lane * 2], n2 = x2 * r * w[lane * 2 + 1];
  float c = cosT[p * 64 + lane], s = sinT[p * 64 + lane];
  f16x2 ov = {(f16)((n1 * c - n2 * s) * osc), (f16)((n1 * s + n2 * c) * osc)};
  *(f16x2*)ptr = ov;
}

// ---------------- flash attention v7: kv-split + exp/PV interleave (r9, best) ----------------
// Grid 840 = 120 cond blocks (kv [0,800)) + 720 noise half-blocks (kv [1600s,1600s+1600)).
// exp of kv-sub-block b+1 is issued inside sub-block b's PV iteration so the
// trans-pipe exps hide under the MFMA stream (they are dependency-free).
__global__ __launch_bounds__(320) void attn7(
    const f16* __restrict__ q, const f16* __restrict__ k, const f16* __restrict__ vt,
    f16* __restrict__ out, f16* __restrict__ Op, float2* __restrict__ ml) {
  __shared__ char smem[65536];
  f16* Ks = (f16*)smem;            // [128 kv][128 d] chunk-swizzled (^ row&15)
  f16* Vs = (f16*)(smem + 32768);  // [128 d][128 kv] chunk-swizzled

  // XCD-chunked remap: 840 = 8 XCD x 105; per XCD 3 heads x (5 cond + 30 noise-halves)
  int L = blockIdx.x;
  int xcd = L & 7, j = L >> 3;         // j 0..104
  int head = xcd * 3 + j / 35;
  int u = j % 35;
  int q0, kv_lo, kv_hi, s = 0;
  bool direct;
  if (u < 5) { q0 = u * 160; kv_lo = 0; kv_hi = 800; direct = true; }
  else {
    int v = u - 5;                     // 0..29
    int qn = v >> 1; s = v & 1;
    q0 = 800 + qn * 160; kv_lo = s * 1600; kv_hi = kv_lo + 1600; direct = false;
  }

  const int tid = threadIdx.x, lane = tid & 63, w = tid >> 6;
  const int l31 = lane & 31, hi = lane >> 5;
  const int qg = q0 + w * 32 + l31;
  const int sw_base = l31 & 15;

  // Q frags (B-side): lane q=l31, d = ks*16 + hi*8 + e (pre-scaled by SCALE*log2e)
  f16x8 qr[8];
#pragma unroll
  for (int ks = 0; ks < 8; ++ks)
    qr[ks] = *(const f16x8*)(q + (size_t)qg * DIM + head * 128 + ks * 16 + hi * 8);

  const f16x8 ones = {(f16)1, (f16)1, (f16)1, (f16)1, (f16)1, (f16)1, (f16)1, (f16)1};

  f32x16 o[4], lsum;
#pragma unroll
  for (int mb = 0; mb < 4; ++mb)
#pragma unroll
    for (int r = 0; r < 16; ++r) o[mb][r] = 0.f;
#pragma unroll
  for (int r = 0; r < 16; ++r) lsum[r] = 0.f;
  float m_run = -1e30f;

  for (int t0 = kv_lo; t0 < kv_hi; t0 += 128) {
    __syncthreads();
    // stage K[128][128] and V^T[128][128], 16B chunks, chunk-XOR swizzle c^(row&15)
#pragma unroll
    for (int r = 0; r < 13; ++r) {
      int idx = r * 320 + tid;
      if (idx < 4096) {
        int row = (idx >> 4) & 127;
        int sw = (idx & 15) ^ (row & 15);
        const f16* src;
        if (idx < 2048) src = k + (size_t)(t0 + row) * DIM + head * 128 + sw * 8;
        else            src = vt + ((size_t)head * 128 + row) * NTOK + t0 + sw * 8;
        async16(src, smem + idx * 16);
      }
    }
    __syncthreads();

    const int nvb = min(4, (kv_hi - t0) >> 5);   // valid 32-kv blocks (>=1)

    // S^T = K . Q^T : D[m=kv][n=q]; lane q=l31
    f32x16 s4[4];
#pragma unroll
    for (int b = 0; b < 4; ++b)
#pragma unroll
      for (int r = 0; r < 16; ++r) s4[b][r] = 0.f;
    __builtin_amdgcn_s_setprio(1);
#pragma unroll
    for (int ks = 0; ks < 8; ++ks) {
#pragma unroll
      for (int b = 0; b < 4; ++b) {
        if (b < nvb) {
          const f16x8 kf = *(const f16x8*)(Ks + ((b * 32 + l31) << 7) +
                                           (((ks * 2 + hi) ^ sw_base) << 3));
          s4[b] = __builtin_amdgcn_mfma_f32_32x32x16_f16(kf, qr[ks], s4[b], 0, 0, 0);
        }
      }
    }
    __builtin_amdgcn_s_setprio(0);

    // tile max + defer-max (single check, log2 domain)
    float tmax = -1e30f;
#pragma unroll
    for (int b = 0; b < 4; ++b)
      if (b < nvb)
#pragma unroll
        for (int r = 0; r < 16; r += 2)
          tmax = fmaxf(tmax, fmaxf(s4[b][r], s4[b][r + 1]));
    tmax = fmaxf(tmax, __shfl_xor(tmax, 32));
    if (!__all(tmax <= m_run + 11.54f)) {          // defer-max (T13), 8 nat in bits
      float mn = fmaxf(m_run, tmax);
      float alpha = fexp2(m_run - mn);
#pragma unroll
      for (int mb = 0; mb < 4; ++mb)
#pragma unroll
        for (int r = 0; r < 16; ++r) o[mb][r] *= alpha;
#pragma unroll
      for (int r = 0; r < 16; ++r) lsum[r] *= alpha;
      m_run = mn;
    }

    // exp b=0 up front; exp b+1 interleaved into b's PV (hides under MFMA)
#pragma unroll
    for (int r = 0; r < 16; ++r) s4[0][r] = fexp2(s4[0][r] - m_run);

    const int nks = nvb * 2;
    __builtin_amdgcn_s_setprio(1);
#pragma unroll
    for (int ks = 0; ks < 8; ++ks) {
      if (ks < nks) {
        const int b = ks >> 1, s8 = (ks & 1) * 8;
        if ((ks & 1) && (b + 1) < nvb) {
#pragma unroll
          for (int r = 0; r < 16; ++r)
            s4[b + 1][r] = fexp2(s4[b + 1][r] - m_run);
        }
        uint32_t a0 = pkrtz(s4[b][s8 + 0], s4[b][s8 + 1]);
        uint32_t b0 = pkrtz(s4[b][s8 + 4], s4[b][s8 + 5]);
        asm("v_permlane32_swap_b32 %0, %1" : "+v"(a0), "+v"(b0));
        uint32_t a1 = pkrtz(s4[b][s8 + 2], s4[b][s8 + 3]);
        uint32_t b1 = pkrtz(s4[b][s8 + 6], s4[b][s8 + 7]);
        asm("v_permlane32_swap_b32 %0, %1" : "+v"(a1), "+v"(b1));
        union { uint32_t u[4]; f16x8 v; } pf2;
        pf2.u[0] = a0; pf2.u[1] = a1; pf2.u[2] = b0; pf2.u[3] = b1;
#pragma unroll
        for (int mb = 0; mb < 4; ++mb) {
          const f16x8 vf = *(const f16x8*)(Vs + ((mb * 32 + l31) << 7) +
                                           (((ks * 2 + hi) ^ sw_base) << 3));
          o[mb] = __builtin_amdgcn_mfma_f32_32x32x16_f16(vf, pf2.v, o[mb], 0, 0, 0);
        }
        lsum = __builtin_amdgcn_mfma_f32_32x32x16_f16(ones, pf2.v, lsum, 0, 0, 0);
      }
    }
    __builtin_amdgcn_s_setprio(0);
  }

  float inv = 1.f / lsum[0];
  // O^T: lane q=l31; d = mb*32 + (r&3) + 8*(r>>2) + 4*hi
  f16* obase = direct
      ? out + (size_t)qg * DIM + head * 128
      : Op + ((size_t)(s * NHEAD + head) * 2400 + (qg - 800)) * 128;
#pragma unroll
  for (int mb = 0; mb < 4; ++mb)
#pragma unroll
    for (int jq = 0; jq < 4; ++jq) {
      f16x4 ov;
#pragma unroll
      for (int e = 0; e < 4; ++e) ov[e] = (f16)(o[mb][jq * 4 + e] * inv);
      *(f16x4*)(obase + mb * 32 + jq * 8 + hi * 4) = ov;
    }
  if (!direct && hi == 0)
    ml[(size_t)(s * NHEAD + head) * 2400 + (qg - 800)] = make_float2(m_run, lsum[0]);
}

// ---------------- merge of the two noise kv-halves ----------------
// out[800+qn][head*128+d] = (O1*w1 + O2*w2)/(w1+w2), w_s = l_s * 2^(m_s - m)
__global__ __launch_bounds__(256) void attn_merge(
    const f16* __restrict__ Op, const float2* __restrict__ ml,
    f16* __restrict__ out) {
  int row = blockIdx.x * 4 + (threadIdx.x >> 6);   // 0..57599 = head*2400 + qn
  int lane = threadIdx.x & 63;
  int head = row / 2400, qn = row % 2400;
  float2 ml1 = ml[row];
  float2 ml2 = ml[24 * 2400 + row];
  float m = fmaxf(ml1.x, ml2.x);
  float w1 = ml1.y * fexp2(ml1.x - m);
  float w2 = ml2.y * fexp2(ml2.x - m);
  float inv = 1.f / (w1 + w2);
  w1 *= inv; w2 *= inv;
  f16x2 o1 = *(const f16x2*)(Op + (size_t)row * 128 + lane * 2);
  f16x2 o2 = *(const f16x2*)(Op + (size_t)(24 * 2400 + row) * 128 + lane * 2);
  f16x2 ov = {(f16)((float)o1[0] * w1 + (float)o2[0] * w2),
              (f16)((float)o1[1] * w1 + (float)o2[1] * w2)};
  *(f16x2*)(out + (size_t)(800 + qn) * DIM + head * 128 + lane * 2) = ov;
}

// ---------------- launcher ----------------

extern "C" void kernel_launch(void* const* d_in, const int* in_sizes, int n_in,
                              void* d_out, int out_size, void* d_ws, size_t ws_size,
                              hipStream_t stream) {
  const float* x   = (const float*)d_in[0];
  const float* Wq  = (const float*)d_in[1];
  const float* bq  = (const float*)d_in[2];
  const float* Wk  = (const float*)d_in[3];
  const float* bk  = (const float*)d_in[4];
  const float* Wv  = (const float*)d_in[5];
  const float* bv  = (const float*)d_in[6];
  const float* Wo  = (const float*)d_in[7];
  const float* bo  = (const float*)d_in[8];
  const float* qnw = (const float*)d_in[9];
  const float* knw = (const float*)d_in[10];
  // d_in[11] = num_cond_latents: fixed 2 per setup -> nct = 800 (grid geometry)

  char* ws = (char*)d_ws;
  f16*   xb   = (f16*)(ws);                       // 19,660,800 B
  f16*   WqT  = (f16*)(ws + 19660800);            // 18,874,368 B each
  f16*   WkT  = (f16*)(ws + 38535168);
  f16*   WvT  = (f16*)(ws + 57409536);
  f16*   WoT  = (f16*)(ws + 76283904);
  f16*   qb   = (f16*)(ws + 95158272);            // 19,660,800 B each
  f16*   kb   = (f16*)(ws + 114819072);
  f16*   vtb  = (f16*)(ws + 134479872);           // V^T [3072][3200]
  f16*   ab   = (f16*)(ws + 154140672);
  float* cosT = (float*)(ws + 173801472);         // 819,200 B each
  float* sinT = (float*)(ws + 174620672);         // end: 175,439,872 B
  // attn partials: reuse xb/WqT region (dead after gemm256_qkv)
  f16*    Op  = (f16*)(ws);                       // [2][24][2400][128] f16 = 29,491,200 B
  float2* ml  = (float2*)(ws + 29491200);         // [2][24][2400] float2 = 921,600 B

  cvt_f32_f16<<<9600, 256, 0, stream>>>(x, xb);
  transpose4<<<dim3(96, 96, 4), 256, 0, stream>>>(Wq, Wk, Wv, Wo, WqT, WkT, WvT, WoT);
  rope_tables<<<800, 256, 0, stream>>>(cosT, sinT);

  gemm256_qkv<<<dim3(13, 36), 512, 0, stream>>>(xb, WqT, WkT, WvT, bq, bk, bv, qb, kb, vtb);

  rmsnorm_rope2<<<dim3(19200, 2), 256, 0, stream>>>(qb, kb, qnw, knw, cosT, sinT);

  attn7<<<840, 320, 0, stream>>>(qb, kb, vtb, ab, Op, ml);
  attn_merge<<<14400, 256, 0, stream>>>(Op, ml, ab);

  gemm256_out<<<dim3(13, 12), 512, 0, stream>>>(ab, WoT, bo, (float*)d_out);
}